// Round 7
// baseline (179.988 us; speedup 1.0000x reference)
//
#include <hip/hip_runtime.h>

#define NEG_SLOPE 0.2f

typedef __attribute__((ext_vector_type(8))) short short8;
typedef __attribute__((ext_vector_type(4))) float floatx4;

__device__ __forceinline__ unsigned f2bf(float x) {
  unsigned u = __float_as_uint(x);
  unsigned r = ((u >> 16) & 1u) + 0x7fffu;
  return (u + r) >> 16;
}
__device__ __forceinline__ float bf2f(unsigned hi16) {
  return __uint_as_float(hi16 << 16);
}

// ---------------- one-shot: W -> MFMA B-fragments (hi/lo) in global ----------------
// entry u = (ct*4+kc)*64 + lane ; element j: B[k=kc*32+(lane>>4)*8+j][n=ct*16+(lane&15)]
__global__ __launch_bounds__(256) void k_prep(const float* __restrict__ W,
                                              uint4* __restrict__ gWf,
                                              int* __restrict__ bsize, int NB2) {
  const int u = blockIdx.x * 256 + threadIdx.x;
  if (blockIdx.x == 0 && threadIdx.x < NB2) bsize[threadIdx.x] = 0;
  if (u >= 2048) return;
  int ln = u & 63;
  int kc = (u >> 6) & 3;
  int ct = u >> 8;
  int n = ct * 16 + (ln & 15);
  int kb = kc * 32 + (ln >> 4) * 8;
  int head = n >> 5;
  const float* src = W + head * 4096 + (size_t)kb * 32 + (n & 31);
  unsigned hi[4], lo[4];
#pragma unroll
  for (int jj = 0; jj < 4; ++jj) {
    float w0 = src[(2 * jj) * 32];
    float w1 = src[(2 * jj + 1) * 32];
    unsigned h0 = f2bf(w0), h1 = f2bf(w1);
    unsigned l0 = f2bf(w0 - bf2f(h0)), l1 = f2bf(w1 - bf2f(h1));
    hi[jj] = h0 | (h1 << 16);
    lo[jj] = l0 | (l1 << 16);
  }
  gWf[u] = make_uint4(hi[0], hi[1], hi[2], hi[3]);
  gWf[2048 + u] = make_uint4(lo[0], lo[1], lo[2], lo[3]);
}

// ---------------- fused: bucket-hist + MFMA projection GEMM + attention dots ----------------
// Split-precision bf16 MFMA: X = Xh + Xl; A*B ~= Ah*Bh + Al*Bh + Ah*Bl.
// Block: 256 thr = 4 waves; 64 rows/block. kc-outer loop with coalesced LDS h-staging.
__global__ __launch_bounds__(256) void k_gemm(const float* __restrict__ h,
                                              const uint4* __restrict__ gWf,
                                              const float* __restrict__ a,
                                              const int* __restrict__ ei,
                                              unsigned short* __restrict__ hp16,
                                              float* __restrict__ ssrc,
                                              float* __restrict__ sdst,
                                              int* __restrict__ bsize,
                                              int N, int E, int NB2) {
  __shared__ unsigned lds_u[16384];  // 64 KB: B-frags hi [0,8192) lo [8192,16384); reused as epilogue buf
  __shared__ float hs[64 * 36];      // 9 KB coalesced h-stage (stride 36: 2-way banks only)
  __shared__ int bh[256];
  const int tid = threadIdx.x;

  // coarse dst-bucket histogram (dst>>8), LDS-aggregated
  for (int i = tid; i < NB2; i += 256) bh[i] = 0;
  __syncthreads();
  for (long long t = (long long)blockIdx.x * 256 + tid; t < E;
       t += (long long)gridDim.x * 256)
    atomicAdd(&bh[ei[E + t] >> 8], 1);

  // stage precomputed W-fragments: plain 16B/lane copies
  for (int u = tid; u < 4096; u += 256)
    *(uint4*)&lds_u[u * 4] = gWf[u];
  __syncthreads();  // bh complete + frags visible

  for (int i = tid; i < NB2; i += 256)
    if (bh[i]) atomicAdd(&bsize[i], bh[i]);

  const int lane = tid & 63;
  const int wv = tid >> 6;
  const int quad = lane >> 4;
  const int l16 = lane & 15;
  const int row0 = blockIdx.x * 64;

  floatx4 C[8];
#pragma unroll
  for (int ct = 0; ct < 8; ++ct) C[ct] = (floatx4){0.f, 0.f, 0.f, 0.f};

  for (int kc = 0; kc < 4; ++kc) {
    __syncthreads();  // previous iteration's hs readers done
    // stage h[row0..row0+63][kc*32..+32) coalesced (128B runs per row)
    for (int idx = tid; idx < 512; idx += 256) {
      int r = idx >> 3, c4 = idx & 7;
      int gr = row0 + r;
      float4 v = make_float4(0.f, 0.f, 0.f, 0.f);
      if (gr < N) v = *(const float4*)&h[(size_t)gr * 128 + kc * 32 + c4 * 4];
      *(float4*)&hs[r * 36 + c4 * 4] = v;
    }
    __syncthreads();
    // build A fragments (hi/lo) from LDS
    short8 Ah, Al;
    {
      const float* hrow = &hs[(wv * 16 + l16) * 36 + quad * 8];
      float4 fa = *(const float4*)hrow;
      float4 fb = *(const float4*)(hrow + 4);
      float v[8] = {fa.x, fa.y, fa.z, fa.w, fb.x, fb.y, fb.z, fb.w};
#pragma unroll
      for (int j = 0; j < 8; ++j) {
        unsigned hi = f2bf(v[j]);
        Ah[j] = (short)hi;
        Al[j] = (short)f2bf(v[j] - bf2f(hi));
      }
    }
#pragma unroll
    for (int ct = 0; ct < 8; ++ct) {
      int bidx = ((ct * 4 + kc) * 64 + lane) * 4;
      short8 Bh, Bl;
      *(uint4*)&Bh = *(const uint4*)&lds_u[bidx];
      *(uint4*)&Bl = *(const uint4*)&lds_u[8192 + bidx];
      C[ct] = __builtin_amdgcn_mfma_f32_16x16x32_bf16(Ah, Bh, C[ct], 0, 0, 0);
      C[ct] = __builtin_amdgcn_mfma_f32_16x16x32_bf16(Al, Bh, C[ct], 0, 0, 0);
      C[ct] = __builtin_amdgcn_mfma_f32_16x16x32_bf16(Ah, Bl, C[ct], 0, 0, 0);
    }
  }
  __syncthreads();  // all waves done reading B-frags; reuse LDS as epilogue buf

  // ---- transpose C through LDS (row stride 132 floats) ----
  float* epi = (float*)lds_u;
#pragma unroll
  for (int ct = 0; ct < 8; ++ct) {
#pragma unroll
    for (int reg = 0; reg < 4; ++reg) {
      int rr = wv * 16 + quad * 4 + reg;
      epi[rr * 132 + ct * 16 + l16] = C[ct][reg];
    }
  }
  __syncthreads();

  // ---- epilogue: 4 threads/row (one per head): a-dots + bf16 pack ----
  const int row_l = tid >> 2;
  const int hh = tid & 3;
  const int rg = row0 + row_l;
  if (rg < N) {
    const float* rowp = &epi[row_l * 132 + hh * 32];
    float ss = 0.f, sd = 0.f;
    unsigned pka[16];
#pragma unroll
    for (int e = 0; e < 8; ++e) {
      float4 c4 = *(const float4*)&rowp[e * 4];
      float4 as = *(const float4*)&a[hh * 64 + e * 4];
      float4 ad = *(const float4*)&a[hh * 64 + 32 + e * 4];
      ss += c4.x * as.x + c4.y * as.y + c4.z * as.z + c4.w * as.w;
      sd += c4.x * ad.x + c4.y * ad.y + c4.z * ad.z + c4.w * ad.w;
      pka[e * 2] = f2bf(c4.x) | (f2bf(c4.y) << 16);
      pka[e * 2 + 1] = f2bf(c4.z) | (f2bf(c4.w) << 16);
    }
    unsigned short* dst = &hp16[(size_t)rg * 128 + hh * 32];
    *(uint4*)(dst) = make_uint4(pka[0], pka[1], pka[2], pka[3]);
    *(uint4*)(dst + 8) = make_uint4(pka[4], pka[5], pka[6], pka[7]);
    *(uint4*)(dst + 16) = make_uint4(pka[8], pka[9], pka[10], pka[11]);
    *(uint4*)(dst + 24) = make_uint4(pka[12], pka[13], pka[14], pka[15]);
    ssrc[(size_t)rg * 4 + hh] = ss;
    sdst[(size_t)rg * 4 + hh] = sd;
  }
}

// ---------------- bucket base scan (NB2 <= 256), single block ----------------
__global__ __launch_bounds__(256) void k_scan_bk(const int* __restrict__ bsize,
                                                 int* __restrict__ bbase,
                                                 int* __restrict__ bcursor, int NB2) {
  __shared__ int lds[256];
  const int tid = threadIdx.x;
  int s = (tid < NB2) ? bsize[tid] : 0;
  lds[tid] = s;
  __syncthreads();
  for (int off = 1; off < 256; off <<= 1) {
    int t = (tid >= off) ? lds[tid - off] : 0;
    __syncthreads();
    lds[tid] += t;
    __syncthreads();
  }
  if (tid < NB2) {
    int excl = lds[tid] - s;
    bbase[tid] = excl;
    bcursor[tid] = excl;
    if (tid == NB2 - 1) bbase[NB2] = lds[tid];
  }
}

// ---------------- pass 1: bin edges by coarse bucket, coalesced pair writes ----------------
__global__ __launch_bounds__(256) void k_bin(const int* __restrict__ ei,
                                             int* __restrict__ bcursor,
                                             uint2* __restrict__ gpairs, int E, int NB2) {
  __shared__ uint2 stage[4096];  // 32 KB
  __shared__ int cnt[256], start[256], cur[256], gbase[256];
  const int tid = threadIdx.x;
  const int e0 = blockIdx.x * 4096;
  for (int i = tid; i < NB2; i += 256) cnt[i] = 0;
  __syncthreads();
  int sarr[16], darr[16];
#pragma unroll
  for (int j = 0; j < 16; ++j) {
    int e = e0 + j * 256 + tid;
    if (e < E) {
      sarr[j] = ei[e];
      darr[j] = ei[E + e];
      atomicAdd(&cnt[darr[j] >> 8], 1);
    } else {
      darr[j] = -1;
    }
  }
  __syncthreads();
  {
    int s = (tid < NB2) ? cnt[tid] : 0;
    __shared__ int lds[256];
    lds[tid] = s;
    __syncthreads();
    for (int off = 1; off < 256; off <<= 1) {
      int t = (tid >= off) ? lds[tid - off] : 0;
      __syncthreads();
      lds[tid] += t;
      __syncthreads();
    }
    if (tid < NB2) {
      start[tid] = lds[tid] - s;
      cur[tid] = lds[tid] - s;
    }
  }
  __syncthreads();
#pragma unroll
  for (int j = 0; j < 16; ++j) {
    if (darr[j] >= 0) {
      int b = darr[j] >> 8;
      int pos = atomicAdd(&cur[b], 1);
      stage[pos] = make_uint2((unsigned)sarr[j], (unsigned)darr[j]);
    }
  }
  if (tid < NB2) {
    int c = cnt[tid];
    gbase[tid] = c ? atomicAdd(&bcursor[tid], c) : 0;
  }
  __syncthreads();
  const int total = start[NB2 - 1] + cnt[NB2 - 1];
  for (int u = tid; u < total; u += 256) {
    uint2 pr = stage[u];
    int b = (int)(pr.y >> 8);
    gpairs[gbase[b] + (u - start[b])] = pr;
  }
}

// ---------------- pass 2: per-bucket counting sort by local dst -> CSR + offs ----------------
__global__ __launch_bounds__(256) void k_build(const int* __restrict__ bbase,
                                               const uint2* __restrict__ gpairs,
                                               int* __restrict__ csr_src,
                                               int* __restrict__ offs, int N) {
  __shared__ int cnt2[256], start2[256], cur2[256];
  __shared__ int srcsort[8192];  // 32 KB; bucket mean ~4082, safe cap
  const int tid = threadIdx.x;
  const int b = blockIdx.x;
  const int base = bbase[b];
  const int size = bbase[b + 1] - base;
  const int d0 = b << 8;
  const int ndst = min(256, N - d0);
  cnt2[tid] = 0;
  __syncthreads();
  for (int u = tid; u < size; u += 256)
    atomicAdd(&cnt2[(int)gpairs[base + u].y - d0], 1);
  __syncthreads();
  {
    int s = cnt2[tid];
    __shared__ int lds[256];
    lds[tid] = s;
    __syncthreads();
    for (int off = 1; off < 256; off <<= 1) {
      int t = (tid >= off) ? lds[tid - off] : 0;
      __syncthreads();
      lds[tid] += t;
      __syncthreads();
    }
    start2[tid] = lds[tid] - s;
    cur2[tid] = lds[tid] - s;
  }
  __syncthreads();
  for (int u = tid; u < size; u += 256) {
    uint2 pr = gpairs[base + u];
    int pos = atomicAdd(&cur2[(int)pr.y - d0], 1);
    srcsort[pos] = (int)pr.x;
  }
  __syncthreads();
  for (int u = tid; u < size; u += 256) csr_src[base + u] = srcsort[u];
  if (tid < ndst) offs[d0 + tid] = base + start2[tid] + cnt2[tid];  // inclusive end
}

// ---------------- aggregation: 16 lanes per dst, 8 ch/lane, single pass ----------------
__global__ __launch_bounds__(256) void k_agg(const int* __restrict__ offs,
                                             const int* __restrict__ csr_src,
                                             const float* __restrict__ ssrc,
                                             const float* __restrict__ sdst,
                                             const uint4* __restrict__ hp4,
                                             float* __restrict__ out, int N) {
  const int t = blockIdx.x * 256 + threadIdx.x;
  const int d = t >> 4;
  if (d >= N) return;
  const int l = threadIdx.x & 15;
  const int hh = l >> 2;
  const int beg = (d == 0) ? 0 : offs[d - 1];
  const int end = offs[d];
  const float sdh = sdst[(size_t)d * 4 + hh];

  float den0 = 0.f, den1 = 0.f;
  float acc[8];
#pragma unroll
  for (int j = 0; j < 8; ++j) acc[j] = 0.f;

  int p = beg;
  for (; p + 1 < end; p += 2) {
    int s0 = csr_src[p];
    int s1 = csr_src[p + 1];
    float sc0 = ssrc[(size_t)s0 * 4 + hh] + sdh;
    float sc1 = ssrc[(size_t)s1 * 4 + hh] + sdh;
    uint4 v0 = hp4[(size_t)s0 * 16 + l];
    uint4 v1 = hp4[(size_t)s1 * 16 + l];
    sc0 = sc0 >= 0.f ? sc0 : NEG_SLOPE * sc0;
    sc1 = sc1 >= 0.f ? sc1 : NEG_SLOPE * sc1;
    float w0 = __expf(sc0);
    float w1 = __expf(sc1);
    den0 += w0;
    den1 += w1;
    acc[0] = fmaf(w0, bf2f(v0.x & 0xffffu), acc[0]);
    acc[1] = fmaf(w0, bf2f(v0.x >> 16), acc[1]);
    acc[2] = fmaf(w0, bf2f(v0.y & 0xffffu), acc[2]);
    acc[3] = fmaf(w0, bf2f(v0.y >> 16), acc[3]);
    acc[4] = fmaf(w0, bf2f(v0.z & 0xffffu), acc[4]);
    acc[5] = fmaf(w0, bf2f(v0.z >> 16), acc[5]);
    acc[6] = fmaf(w0, bf2f(v0.w & 0xffffu), acc[6]);
    acc[7] = fmaf(w0, bf2f(v0.w >> 16), acc[7]);
    acc[0] = fmaf(w1, bf2f(v1.x & 0xffffu), acc[0]);
    acc[1] = fmaf(w1, bf2f(v1.x >> 16), acc[1]);
    acc[2] = fmaf(w1, bf2f(v1.y & 0xffffu), acc[2]);
    acc[3] = fmaf(w1, bf2f(v1.y >> 16), acc[3]);
    acc[4] = fmaf(w1, bf2f(v1.z & 0xffffu), acc[4]);
    acc[5] = fmaf(w1, bf2f(v1.z >> 16), acc[5]);
    acc[6] = fmaf(w1, bf2f(v1.w & 0xffffu), acc[6]);
    acc[7] = fmaf(w1, bf2f(v1.w >> 16), acc[7]);
  }
  if (p < end) {
    int s0 = csr_src[p];
    float sc0 = ssrc[(size_t)s0 * 4 + hh] + sdh;
    uint4 v0 = hp4[(size_t)s0 * 16 + l];
    sc0 = sc0 >= 0.f ? sc0 : NEG_SLOPE * sc0;
    float w0 = __expf(sc0);
    den0 += w0;
    acc[0] = fmaf(w0, bf2f(v0.x & 0xffffu), acc[0]);
    acc[1] = fmaf(w0, bf2f(v0.x >> 16), acc[1]);
    acc[2] = fmaf(w0, bf2f(v0.y & 0xffffu), acc[2]);
    acc[3] = fmaf(w0, bf2f(v0.y >> 16), acc[3]);
    acc[4] = fmaf(w0, bf2f(v0.z & 0xffffu), acc[4]);
    acc[5] = fmaf(w0, bf2f(v0.z >> 16), acc[5]);
    acc[6] = fmaf(w0, bf2f(v0.w & 0xffffu), acc[6]);
    acc[7] = fmaf(w0, bf2f(v0.w >> 16), acc[7]);
  }
  float rden = 1.f / fmaxf(den0 + den1, 1e-16f);
  float o[8];
#pragma unroll
  for (int j = 0; j < 8; ++j) {
    float x = acc[j] * rden;
    o[j] = x > 0.f ? x : expm1f(x);
  }
  float* dst = &out[(size_t)d * 128 + l * 8];
  *(float4*)dst = make_float4(o[0], o[1], o[2], o[3]);
  *(float4*)(dst + 4) = make_float4(o[4], o[5], o[6], o[7]);
}

extern "C" void kernel_launch(void* const* d_in, const int* in_sizes, int n_in,
                              void* d_out, int out_size, void* d_ws, size_t ws_size,
                              hipStream_t stream) {
  const float* h = (const float*)d_in[0];
  const int* ei = (const int*)d_in[1];
  const float* W = (const float*)d_in[2];
  const float* a = (const float*)d_in[3];
  float* out = (float*)d_out;
  const int N = in_sizes[0] / 128;
  const int E = in_sizes[1] / 2;
  const int NB2 = (N + 255) >> 8;          // coarse buckets (dst>>8), <=256
  const int NB1 = (E + 4095) / 4096;       // bin blocks

  char* ws = (char*)d_ws;
  uint4* gWf = (uint4*)ws;                               // 4096 (64 KB)
  unsigned short* hp16 = (unsigned short*)(gWf + 4096);  // N*128 bf16
  uint2* gpairs = (uint2*)(hp16 + (size_t)N * 128);      // E pairs
  float* ssrc = (float*)(gpairs + (size_t)E);            // N*4
  float* sdst = ssrc + (size_t)N * 4;                    // N*4
  int* bsize = (int*)(sdst + (size_t)N * 4);             // NB2
  int* bbase = bsize + NB2;                              // NB2+1
  int* bcursor = bbase + NB2 + 1;                        // NB2
  int* offs = bcursor + NB2;                             // N
  int* csr_src = offs + N;                               // E

  k_prep<<<8, 256, 0, stream>>>(W, gWf, bsize, NB2);
  k_gemm<<<(N + 63) / 64, 256, 0, stream>>>(h, gWf, a, ei, hp16, ssrc, sdst, bsize, N, E, NB2);
  k_scan_bk<<<1, 256, 0, stream>>>(bsize, bbase, bcursor, NB2);
  k_bin<<<NB1, 256, 0, stream>>>(ei, bcursor, gpairs, E, NB2);
  k_build<<<NB2, 256, 0, stream>>>(bbase, gpairs, csr_src, offs, N);
  k_agg<<<(N * 16 + 255) / 256, 256, 0, stream>>>(offs, csr_src, ssrc, sdst,
                                                  (const uint4*)hp16, out, N);
}